// Round 8
// baseline (372.190 us; speedup 1.0000x reference)
//
#include <hip/hip_runtime.h>

// Problem constants
constexpr int M_ROWS = 512;      // B*N keyword rows
constexpr int D_IN   = 768;
constexpr int T_DIM  = 512;
constexpr int V_SIZE = 49408;    // = 772 * 64
constexpr int NK16   = T_DIM / 16;   // 32 k16-blocks
constexpr float EPS  = 1e-8f;

typedef short bf16x8 __attribute__((ext_vector_type(8)));
typedef float f32x16 __attribute__((ext_vector_type(16)));

__device__ inline unsigned short bf16_rne(float f) {
  unsigned int u = __float_as_uint(f);
  u += 0x7FFFu + ((u >> 16) & 1u);
  return (unsigned short)(u >> 16);
}
__device__ inline float bf16_f32(unsigned short h) {
  return __uint_as_float(((unsigned int)h) << 16);
}
__device__ inline unsigned int f32_sortable(float f) {
  unsigned int u = __float_as_uint(f);
  return (u & 0x80000000u) ? ~u : (u | 0x80000000u);
}
__device__ inline unsigned long long shfl_xor_u64(unsigned long long x, int mask) {
  unsigned int lo = (unsigned int)(x & 0xFFFFFFFFull);
  unsigned int hi = (unsigned int)(x >> 32);
  lo = __shfl_xor(lo, mask);
  hi = __shfl_xor(hi, mask);
  return ((unsigned long long)hi << 32) | (unsigned long long)lo;
}

// MFMA 32x32x16 fragment address: slot-major [tile32*NK16 + k16][lanepos][8]
// lanepos = (rc & 31) | (((k >> 3) & 1) << 5), j = k & 7
__device__ inline size_t frag_idx(int tile_slot, int rc, int k) {
  return (size_t)tile_slot * 512 +
         (size_t)(((rc & 31) | (((k >> 3) & 1) << 5)) * 8) + (k & 7);
}

// ---------------- Kernel 1: proj kw = audio @ W + b -> bf16 hi/lo (frag order) ----
__global__ __launch_bounds__(256) void proj_kernel(
    const float* __restrict__ audio, const float* __restrict__ W,
    const float* __restrict__ bias, unsigned short* __restrict__ kwH,
    unsigned short* __restrict__ kwL) {
  __shared__ float a[4][D_IN];  // 12 KB
  const int tid = threadIdx.x;
  const int m0 = blockIdx.x * 4;

  const float4* src4 = reinterpret_cast<const float4*>(audio + (size_t)m0 * D_IN);
  float4* a4 = reinterpret_cast<float4*>(&a[0][0]);
  #pragma unroll
  for (int i = 0; i < 3; ++i) a4[tid + 256 * i] = src4[tid + 256 * i];
  __syncthreads();

  const int t0 = tid, t1 = tid + 256;
  float acc[4][2] = {};
  #pragma unroll 4
  for (int d = 0; d < D_IN; ++d) {
    const float w0 = W[(size_t)d * T_DIM + t0];
    const float w1 = W[(size_t)d * T_DIM + t1];
    #pragma unroll
    for (int r = 0; r < 4; ++r) {
      acc[r][0] = fmaf(a[r][d], w0, acc[r][0]);
      acc[r][1] = fmaf(a[r][d], w1, acc[r][1]);
    }
  }
  const float b0 = bias[t0], b1 = bias[t1];
  #pragma unroll
  for (int r = 0; r < 4; ++r) {
    const int row = m0 + r;
    const float v0 = acc[r][0] + b0;
    const float v1 = acc[r][1] + b1;
    const unsigned short h0 = bf16_rne(v0);
    const unsigned short h1 = bf16_rne(v1);
    const size_t i0 = frag_idx((row >> 5) * NK16 + (t0 >> 4), row, t0);
    const size_t i1 = frag_idx((row >> 5) * NK16 + (t1 >> 4), row, t1);
    kwH[i0] = h0; kwH[i1] = h1;
    kwL[i0] = bf16_rne(v0 - bf16_f32(h0));
    kwL[i1] = bf16_rne(v1 - bf16_f32(h1));
  }
}

// ---------------- Kernel 2: fused scoring: raw-emb staging + self-norm + argmax ----
// BM=512 (ALL rows) x BN=64, BK=32, 16 chunks. Grid = 772 blocks, 4 waves.
// Wave w owns rows [w*128, +128) (4 rt subtiles) x 64 cols (2 ct subtiles).
// Staging: each thread loads 8 raw f32 emb values/chunk, accumulates sum-of-squares
// for its column, converts to bf16 hi/lo, writes LDS. inv_norm applied in epilogue
// (per-column scale commutes through the dot product). emb is read from HBM ONCE.
__global__ __launch_bounds__(256, 2) void score_kernel(
    const unsigned short* __restrict__ kwHf, const unsigned short* __restrict__ kwLf,
    const float* __restrict__ emb, unsigned long long* __restrict__ best) {
  __shared__ short ldsB[2][8][512];  // [buf][(k16o*2+v32o)*2+hl][lanepos*8+j] = 16 KB
  __shared__ float lds_ss[4][32];    // [v32o*2+k16o][col5]

  const int tid  = threadIdx.x;
  const int lane = tid & 63;
  const int w    = tid >> 6;
  const int vb   = blockIdx.x;  // vocab 64-tile

  // staging map: col5 | khalf | k16o | v32o from tid bits
  const int col5  = tid & 31;
  const int khalf = (tid >> 5) & 1;
  const int k16o  = (tid >> 6) & 1;
  const int v32o  = tid >> 7;
  const float* gp =
      emb + (size_t)(vb * 64 + v32o * 32 + col5) * T_DIM + k16o * 16 + khalf * 8;
  const int wrOff = ((k16o * 2 + v32o) * 2) * 512 + ((col5 | (khalf << 5)) * 8);

  // A fragment bases: R32-tile = w*4 + rt (covers rows w*128 .. +128)
  const unsigned short* aHp[4];
  const unsigned short* aLp[4];
  #pragma unroll
  for (int rt = 0; rt < 4; ++rt) {
    const size_t base = (size_t)(w * 4 + rt) * NK16 * 512 + (size_t)lane * 8;
    aHp[rt] = kwHf + base;
    aLp[rt] = kwLf + base;
  }

  f32x16 acc[4][2];
  #pragma unroll
  for (int rt = 0; rt < 4; ++rt)
    #pragma unroll
    for (int ct = 0; ct < 2; ++ct)
      #pragma unroll
      for (int i = 0; i < 16; ++i) acc[rt][ct][i] = 0.0f;

  float ss = 0.0f;
  float4 x0, x1;

  // ---- prologue: stage chunk 0 into buf 0 ----
  x0 = *reinterpret_cast<const float4*>(gp);
  x1 = *reinterpret_cast<const float4*>(gp + 4);
  {
    ss += x0.x * x0.x + x0.y * x0.y + x0.z * x0.z + x0.w * x0.w +
          x1.x * x1.x + x1.y * x1.y + x1.z * x1.z + x1.w * x1.w;
    const float xv[8] = {x0.x, x0.y, x0.z, x0.w, x1.x, x1.y, x1.z, x1.w};
    bf16x8 hv, lv;
    #pragma unroll
    for (int j = 0; j < 8; ++j) {
      const unsigned short h = bf16_rne(xv[j]);
      hv[j] = (short)h;
      lv[j] = (short)bf16_rne(xv[j] - bf16_f32(h));
    }
    short* b0 = &ldsB[0][0][0];
    *reinterpret_cast<bf16x8*>(b0 + wrOff) = hv;
    *reinterpret_cast<bf16x8*>(b0 + wrOff + 512) = lv;
  }
  __syncthreads();

  // ---- main loop: 16 chunks of K=32 ----
  for (int ci = 0; ci < 16; ++ci) {
    const int buf = ci & 1;

    // early-issue next chunk's raw loads (hide HBM latency under MFMA)
    if (ci < 15) {
      x0 = *reinterpret_cast<const float4*>(gp + (ci + 1) * 32);
      x1 = *reinterpret_cast<const float4*>(gp + (ci + 1) * 32 + 4);
    }

    const short* bb = &ldsB[buf][0][0];
    #pragma unroll
    for (int ks = 0; ks < 2; ++ks) {
      bf16x8 aH[4], aL[4];
      #pragma unroll
      for (int rt = 0; rt < 4; ++rt) {
        aH[rt] = *reinterpret_cast<const bf16x8*>(aHp[rt] + (size_t)(ci * 2 + ks) * 512);
        aL[rt] = *reinterpret_cast<const bf16x8*>(aLp[rt] + (size_t)(ci * 2 + ks) * 512);
      }
      #pragma unroll
      for (int ct = 0; ct < 2; ++ct) {
        const bf16x8 bH = *reinterpret_cast<const bf16x8*>(
            bb + ((ks * 2 + ct) * 2 + 0) * 512 + lane * 8);
        const bf16x8 bL = *reinterpret_cast<const bf16x8*>(
            bb + ((ks * 2 + ct) * 2 + 1) * 512 + lane * 8);
        #pragma unroll
        for (int rt = 0; rt < 4; ++rt) {
          acc[rt][ct] = __builtin_amdgcn_mfma_f32_32x32x16_bf16(aH[rt], bH, acc[rt][ct], 0, 0, 0);
          acc[rt][ct] = __builtin_amdgcn_mfma_f32_32x32x16_bf16(aH[rt], bL, acc[rt][ct], 0, 0, 0);
          acc[rt][ct] = __builtin_amdgcn_mfma_f32_32x32x16_bf16(aL[rt], bH, acc[rt][ct], 0, 0, 0);
        }
      }
    }

    // convert + write next chunk into buf^1 (its readers finished last barrier)
    if (ci < 15) {
      ss += x0.x * x0.x + x0.y * x0.y + x0.z * x0.z + x0.w * x0.w +
            x1.x * x1.x + x1.y * x1.y + x1.z * x1.z + x1.w * x1.w;
      const float xv[8] = {x0.x, x0.y, x0.z, x0.w, x1.x, x1.y, x1.z, x1.w};
      bf16x8 hv, lv;
      #pragma unroll
      for (int j = 0; j < 8; ++j) {
        const unsigned short h = bf16_rne(xv[j]);
        hv[j] = (short)h;
        lv[j] = (short)bf16_rne(xv[j] - bf16_f32(h));
      }
      short* bn = &ldsB[buf ^ 1][0][0];
      *reinterpret_cast<bf16x8*>(bn + wrOff) = hv;
      *reinterpret_cast<bf16x8*>(bn + wrOff + 512) = lv;
    }
    __syncthreads();
  }

  // ---- column norms: reduce ss over khalf (lane^32), then across k16o via LDS ----
  ss += __shfl_xor(ss, 32);
  if (lane < 32) lds_ss[w][lane] = ss;  // w = v32o*2 + k16o
  __syncthreads();

  const int c5 = lane & 31;
  float inv[2];
  #pragma unroll
  for (int ct = 0; ct < 2; ++ct) {
    const float sst = lds_ss[ct * 2][c5] + lds_ss[ct * 2 + 1][c5];
    inv[ct] = 1.0f / fmaxf(sqrtf(sst), EPS);
  }

  // ---- epilogue: argmax. C/D: col = lane&31, row = (reg&3)+8*(reg>>2)+4*(lane>>5)
  #pragma unroll
  for (int rt = 0; rt < 4; ++rt) {
    const int rowbase = w * 128 + rt * 32 + 4 * (lane >> 5);
    #pragma unroll
    for (int reg = 0; reg < 16; ++reg) {
      const int row = rowbase + (reg & 3) + 8 * (reg >> 2);
      unsigned long long pk = 0;
      #pragma unroll
      for (int ct = 0; ct < 2; ++ct) {
        const float s = acc[rt][ct][reg] * inv[ct];
        const unsigned long long p =
            ((unsigned long long)f32_sortable(s) << 32) |
            (unsigned long long)(0xFFFFFFFFu - (unsigned)(vb * 64 + ct * 32 + c5));
        if (p > pk) pk = p;
      }
      #pragma unroll
      for (int off = 1; off < 32; off <<= 1) {
        const unsigned long long o = shfl_xor_u64(pk, off);
        if (o > pk) pk = o;
      }
      if (c5 == 0) atomicMax(&best[row], pk);
    }
  }
}

// ---------------- Kernel 3: gather out[row] = token_emb[best[row]] ----------------
__global__ __launch_bounds__(128) void gather_kernel(
    const float* __restrict__ emb, const unsigned long long* __restrict__ best,
    float* __restrict__ out) {
  const int row = blockIdx.x;
  const unsigned int idx =
      0xFFFFFFFFu - (unsigned int)(best[row] & 0xFFFFFFFFull);
  const float4* src = reinterpret_cast<const float4*>(emb + (size_t)idx * T_DIM);
  float4* dst = reinterpret_cast<float4*>(out + (size_t)row * T_DIM);
  dst[threadIdx.x] = src[threadIdx.x];
}

// ---------------- launch ----------------
extern "C" void kernel_launch(void* const* d_in, const int* in_sizes, int n_in,
                              void* d_out, int out_size, void* d_ws, size_t ws_size,
                              hipStream_t stream) {
  const float* audio = (const float*)d_in[0];  // [512, 768]
  const float* Wp    = (const float*)d_in[1];  // [768, 512]
  const float* bp    = (const float*)d_in[2];  // [512]
  const float* emb   = (const float*)d_in[3];  // [49408, 512]
  float* out = (float*)d_out;                  // [512, 512]

  const size_t kw_elems = (size_t)M_ROWS * T_DIM;  // 262144
  char* ws = (char*)d_ws;
  unsigned short* kwHf = (unsigned short*)ws;                 // 512 KB
  unsigned short* kwLf = kwHf + kw_elems;                     // 512 KB
  unsigned long long* best = (unsigned long long*)(kwLf + kw_elems);  // 4 KB

  hipMemsetAsync(best, 0, M_ROWS * sizeof(unsigned long long), stream);

  proj_kernel<<<M_ROWS / 4, 256, 0, stream>>>(audio, Wp, bp, kwHf, kwLf);
  score_kernel<<<V_SIZE / 64, 256, 0, stream>>>(kwHf, kwLf, emb, best);
  gather_kernel<<<M_ROWS, 128, 0, stream>>>(emb, best, out);
}

// Round 9
// 366.931 us; speedup vs baseline: 1.0143x; 1.0143x over previous
//
#include <hip/hip_runtime.h>

// Problem constants
constexpr int M_ROWS = 512;      // B*N keyword rows
constexpr int D_IN   = 768;
constexpr int T_DIM  = 512;
constexpr int V_SIZE = 49408;    // = 772 * 64
constexpr int NK16   = T_DIM / 16;   // 32 k16-blocks
constexpr float EPS  = 1e-8f;

typedef short bf16x8 __attribute__((ext_vector_type(8)));
typedef float f32x16 __attribute__((ext_vector_type(16)));

__device__ inline unsigned short bf16_rne(float f) {
  unsigned int u = __float_as_uint(f);
  u += 0x7FFFu + ((u >> 16) & 1u);
  return (unsigned short)(u >> 16);
}
__device__ inline float bf16_f32(unsigned short h) {
  return __uint_as_float(((unsigned int)h) << 16);
}
__device__ inline unsigned int f32_sortable(float f) {
  unsigned int u = __float_as_uint(f);
  return (u & 0x80000000u) ? ~u : (u | 0x80000000u);
}
__device__ inline unsigned long long shfl_xor_u64(unsigned long long x, int mask) {
  unsigned int lo = (unsigned int)(x & 0xFFFFFFFFull);
  unsigned int hi = (unsigned int)(x >> 32);
  lo = __shfl_xor(lo, mask);
  hi = __shfl_xor(hi, mask);
  return ((unsigned long long)hi << 32) | (unsigned long long)lo;
}

// MFMA 32x32x16 fragment address: slot-major [tile32*NK16 + k16][lanepos][8]
// lanepos = (rc & 31) | (((k >> 3) & 1) << 5), j = k & 7
__device__ inline size_t frag_idx(int tile_slot, int rc, int k) {
  return (size_t)tile_slot * 512 +
         (size_t)(((rc & 31) | (((k >> 3) & 1) << 5)) * 8) + (k & 7);
}

// ---------------- Kernel 1: proj kw = audio @ W + b -> bf16 hi/lo (frag order) ----
__global__ __launch_bounds__(256) void proj_kernel(
    const float* __restrict__ audio, const float* __restrict__ W,
    const float* __restrict__ bias, unsigned short* __restrict__ kwH,
    unsigned short* __restrict__ kwL) {
  __shared__ float a[4][D_IN];  // 12 KB
  const int tid = threadIdx.x;
  const int m0 = blockIdx.x * 4;

  const float4* src4 = reinterpret_cast<const float4*>(audio + (size_t)m0 * D_IN);
  float4* a4 = reinterpret_cast<float4*>(&a[0][0]);
  #pragma unroll
  for (int i = 0; i < 3; ++i) a4[tid + 256 * i] = src4[tid + 256 * i];
  __syncthreads();

  const int t0 = tid, t1 = tid + 256;
  float acc[4][2] = {};
  #pragma unroll 4
  for (int d = 0; d < D_IN; ++d) {
    const float w0 = W[(size_t)d * T_DIM + t0];
    const float w1 = W[(size_t)d * T_DIM + t1];
    #pragma unroll
    for (int r = 0; r < 4; ++r) {
      acc[r][0] = fmaf(a[r][d], w0, acc[r][0]);
      acc[r][1] = fmaf(a[r][d], w1, acc[r][1]);
    }
  }
  const float b0 = bias[t0], b1 = bias[t1];
  #pragma unroll
  for (int r = 0; r < 4; ++r) {
    const int row = m0 + r;
    const float v0 = acc[r][0] + b0;
    const float v1 = acc[r][1] + b1;
    const unsigned short h0 = bf16_rne(v0);
    const unsigned short h1 = bf16_rne(v1);
    const size_t i0 = frag_idx((row >> 5) * NK16 + (t0 >> 4), row, t0);
    const size_t i1 = frag_idx((row >> 5) * NK16 + (t1 >> 4), row, t1);
    kwH[i0] = h0; kwH[i1] = h1;
    kwL[i0] = bf16_rne(v0 - bf16_f32(h0));
    kwL[i1] = bf16_rne(v1 - bf16_f32(h1));
  }
}

// ---------------- Kernel 2: fused scoring, 2-deep prefetch pipeline ----------------
// BM=512 (ALL rows) x BN=64, BK=32, 16 chunks, grid 772, 4 waves.
// Wave w owns rows [w*128,+128) x 64 cols. emb read from HBM ONCE; per-chunk raw
// f32 loads are issued TWO chunks ahead (slots xA=even, xB=odd), so the
// convert->LDS of chunk c+1 sees data loaded 2 MFMA phases ago (HBM latency
// fully covered). Column inv-norms accumulated during conversion, applied in
// the argmax epilogue (per-column scale commutes through the dot product).
__global__ __launch_bounds__(256, 2) void score_kernel(
    const unsigned short* __restrict__ kwHf, const unsigned short* __restrict__ kwLf,
    const float* __restrict__ emb, unsigned long long* __restrict__ best) {
  __shared__ short ldsB[2][8][512];  // [buf][(k16o*2+v32o)*2+hl][lanepos*8+j] = 16 KB
  __shared__ float lds_ss[4][32];    // [v32o*2+k16o][col5]

  const int tid  = threadIdx.x;
  const int lane = tid & 63;
  const int w    = tid >> 6;
  const int vb   = blockIdx.x;  // vocab 64-tile

  // staging map: col5 | khalf | k16o | v32o from tid bits
  const int col5  = tid & 31;
  const int khalf = (tid >> 5) & 1;
  const int k16o  = (tid >> 6) & 1;
  const int v32o  = tid >> 7;
  const float* gp =
      emb + (size_t)(vb * 64 + v32o * 32 + col5) * T_DIM + k16o * 16 + khalf * 8;
  const int wrOff = ((k16o * 2 + v32o) * 2) * 512 + ((col5 | (khalf << 5)) * 8);

  // A fragment bases: R32-tile = w*4 + rt (covers rows w*128 .. +128)
  const unsigned short* aHp[4];
  const unsigned short* aLp[4];
  #pragma unroll
  for (int rt = 0; rt < 4; ++rt) {
    const size_t base = (size_t)(w * 4 + rt) * NK16 * 512 + (size_t)lane * 8;
    aHp[rt] = kwHf + base;
    aLp[rt] = kwLf + base;
  }

  f32x16 acc[4][2];
  #pragma unroll
  for (int rt = 0; rt < 4; ++rt)
    #pragma unroll
    for (int ct = 0; ct < 2; ++ct)
      #pragma unroll
      for (int i = 0; i < 16; ++i) acc[rt][ct][i] = 0.0f;

  float ss = 0.0f;

  // 48 MFMA on LDS buffer bb for K-chunk ci
  auto do_mfma = [&](const short* bb, int ci) {
    #pragma unroll
    for (int ks = 0; ks < 2; ++ks) {
      bf16x8 aH[4], aL[4];
      #pragma unroll
      for (int rt = 0; rt < 4; ++rt) {
        aH[rt] = *reinterpret_cast<const bf16x8*>(aHp[rt] + (size_t)(ci * 2 + ks) * 512);
        aL[rt] = *reinterpret_cast<const bf16x8*>(aLp[rt] + (size_t)(ci * 2 + ks) * 512);
      }
      #pragma unroll
      for (int ct = 0; ct < 2; ++ct) {
        const bf16x8 bH = *reinterpret_cast<const bf16x8*>(
            bb + ((ks * 2 + ct) * 2 + 0) * 512 + lane * 8);
        const bf16x8 bL = *reinterpret_cast<const bf16x8*>(
            bb + ((ks * 2 + ct) * 2 + 1) * 512 + lane * 8);
        #pragma unroll
        for (int rt = 0; rt < 4; ++rt) {
          acc[rt][ct] = __builtin_amdgcn_mfma_f32_32x32x16_bf16(aH[rt], bH, acc[rt][ct], 0, 0, 0);
          acc[rt][ct] = __builtin_amdgcn_mfma_f32_32x32x16_bf16(aH[rt], bL, acc[rt][ct], 0, 0, 0);
          acc[rt][ct] = __builtin_amdgcn_mfma_f32_32x32x16_bf16(aL[rt], bH, acc[rt][ct], 0, 0, 0);
        }
      }
    }
  };

  // convert one staged chunk (2x float4) -> bf16 hi/lo into LDS buffer bn
  auto do_convert = [&](const float4& y0, const float4& y1, short* bn) {
    ss += y0.x * y0.x + y0.y * y0.y + y0.z * y0.z + y0.w * y0.w +
          y1.x * y1.x + y1.y * y1.y + y1.z * y1.z + y1.w * y1.w;
    const float xv[8] = {y0.x, y0.y, y0.z, y0.w, y1.x, y1.y, y1.z, y1.w};
    bf16x8 hv, lv;
    #pragma unroll
    for (int j = 0; j < 8; ++j) {
      const unsigned short h = bf16_rne(xv[j]);
      hv[j] = (short)h;
      lv[j] = (short)bf16_rne(xv[j] - bf16_f32(h));
    }
    *reinterpret_cast<bf16x8*>(bn + wrOff) = hv;
    *reinterpret_cast<bf16x8*>(bn + wrOff + 512) = lv;
  };

  short* buf0 = &ldsB[0][0][0];
  short* buf1 = &ldsB[1][0][0];
  float4 xA0, xA1, xB0, xB1;  // slot A = even chunks, slot B = odd chunks

  // ---- prologue: chunk0 -> buf0; chunk1 load in flight ----
  xA0 = *reinterpret_cast<const float4*>(gp);
  xA1 = *reinterpret_cast<const float4*>(gp + 4);
  do_convert(xA0, xA1, buf0);
  xB0 = *reinterpret_cast<const float4*>(gp + 32);
  xB1 = *reinterpret_cast<const float4*>(gp + 36);
  __syncthreads();

  // ---- main loop: 8 even/odd pairs ----
  for (int it = 0; it < 8; ++it) {
    const int c0 = it * 2;

    // even step: compute chunk c0 (buf0); prefetch c0+2 -> xA; convert c0+1 -> buf1
    if (c0 + 2 < 16) {
      xA0 = *reinterpret_cast<const float4*>(gp + (c0 + 2) * 32);
      xA1 = *reinterpret_cast<const float4*>(gp + (c0 + 2) * 32 + 4);
    }
    do_mfma(buf0, c0);
    do_convert(xB0, xB1, buf1);
    __syncthreads();

    // odd step: compute chunk c0+1 (buf1); prefetch c0+3 -> xB; convert c0+2 -> buf0
    const int c1 = c0 + 1;
    if (c1 + 2 < 16) {
      xB0 = *reinterpret_cast<const float4*>(gp + (c1 + 2) * 32);
      xB1 = *reinterpret_cast<const float4*>(gp + (c1 + 2) * 32 + 4);
    }
    do_mfma(buf1, c1);
    if (c1 < 15) do_convert(xA0, xA1, buf0);
    __syncthreads();
  }

  // ---- column norms: reduce ss over khalf (lane^32), then across k16o via LDS ----
  ss += __shfl_xor(ss, 32);
  if (lane < 32) lds_ss[w][lane] = ss;  // w = v32o*2 + k16o
  __syncthreads();

  const int c5 = lane & 31;
  float inv[2];
  #pragma unroll
  for (int ct = 0; ct < 2; ++ct) {
    const float sst = lds_ss[ct * 2][c5] + lds_ss[ct * 2 + 1][c5];
    inv[ct] = 1.0f / fmaxf(sqrtf(sst), EPS);
  }

  // ---- epilogue: argmax. C/D: col = lane&31, row = (reg&3)+8*(reg>>2)+4*(lane>>5)
  #pragma unroll
  for (int rt = 0; rt < 4; ++rt) {
    const int rowbase = w * 128 + rt * 32 + 4 * (lane >> 5);
    #pragma unroll
    for (int reg = 0; reg < 16; ++reg) {
      const int row = rowbase + (reg & 3) + 8 * (reg >> 2);
      unsigned long long pk = 0;
      #pragma unroll
      for (int ct = 0; ct < 2; ++ct) {
        const float s = acc[rt][ct][reg] * inv[ct];
        const unsigned long long p =
            ((unsigned long long)f32_sortable(s) << 32) |
            (unsigned long long)(0xFFFFFFFFu - (unsigned)(vb * 64 + ct * 32 + c5));
        if (p > pk) pk = p;
      }
      #pragma unroll
      for (int off = 1; off < 32; off <<= 1) {
        const unsigned long long o = shfl_xor_u64(pk, off);
        if (o > pk) pk = o;
      }
      if (c5 == 0) atomicMax(&best[row], pk);
    }
  }
}

// ---------------- Kernel 3: gather out[row] = token_emb[best[row]] ----------------
__global__ __launch_bounds__(128) void gather_kernel(
    const float* __restrict__ emb, const unsigned long long* __restrict__ best,
    float* __restrict__ out) {
  const int row = blockIdx.x;
  const unsigned int idx =
      0xFFFFFFFFu - (unsigned int)(best[row] & 0xFFFFFFFFull);
  const float4* src = reinterpret_cast<const float4*>(emb + (size_t)idx * T_DIM);
  float4* dst = reinterpret_cast<float4*>(out + (size_t)row * T_DIM);
  dst[threadIdx.x] = src[threadIdx.x];
}

// ---------------- launch ----------------
extern "C" void kernel_launch(void* const* d_in, const int* in_sizes, int n_in,
                              void* d_out, int out_size, void* d_ws, size_t ws_size,
                              hipStream_t stream) {
  const float* audio = (const float*)d_in[0];  // [512, 768]
  const float* Wp    = (const float*)d_in[1];  // [768, 512]
  const float* bp    = (const float*)d_in[2];  // [512]
  const float* emb   = (const float*)d_in[3];  // [49408, 512]
  float* out = (float*)d_out;                  // [512, 512]

  const size_t kw_elems = (size_t)M_ROWS * T_DIM;  // 262144
  char* ws = (char*)d_ws;
  unsigned short* kwHf = (unsigned short*)ws;                 // 512 KB
  unsigned short* kwLf = kwHf + kw_elems;                     // 512 KB
  unsigned long long* best = (unsigned long long*)(kwLf + kw_elems);  // 4 KB

  hipMemsetAsync(best, 0, M_ROWS * sizeof(unsigned long long), stream);

  proj_kernel<<<M_ROWS / 4, 256, 0, stream>>>(audio, Wp, bp, kwHf, kwLf);
  score_kernel<<<V_SIZE / 64, 256, 0, stream>>>(kwHf, kwLf, emb, best);
  gather_kernel<<<M_ROWS, 128, 0, stream>>>(emb, best, out);
}